// Round 3
// baseline (825.822 us; speedup 1.0000x reference)
//
#include <hip/hip_runtime.h>

typedef __attribute__((ext_vector_type(8))) short bf16x8;
typedef __attribute__((ext_vector_type(4))) short s16x4;
typedef __attribute__((ext_vector_type(4))) float f32x4;

#define MFMA16(a,b,c) __builtin_amdgcn_mfma_f32_16x16x32_bf16((a),(b),(c),0,0,0)

__device__ __forceinline__ unsigned short f2bf(float f) {
  unsigned int u = __float_as_uint(f);
  return (unsigned short)((u + 0x7fffu + ((u >> 16) & 1u)) >> 16);  // RNE
}

__device__ __forceinline__ void gload16(const void* g, void* l) {
  __builtin_amdgcn_global_load_lds((const __attribute__((address_space(1))) void*)g,
                                   (__attribute__((address_space(3))) void*)l, 16, 0, 0);
}

// ---- f32 -> bf16 bulk convert ----
__global__ __launch_bounds__(256) void cvt_bf16(const float* __restrict__ in,
                                                unsigned short* __restrict__ out, int n8) {
  for (int i = blockIdx.x * 256 + threadIdx.x; i < n8; i += gridDim.x * 256) {
    float4 a = ((const float4*)in)[2 * i];
    float4 b = ((const float4*)in)[2 * i + 1];
    s16x4 p0, p1;
    p0[0] = f2bf(a.x); p0[1] = f2bf(a.y); p0[2] = f2bf(a.z); p0[3] = f2bf(a.w);
    p1[0] = f2bf(b.x); p1[1] = f2bf(b.y); p1[2] = f2bf(b.z); p1[3] = f2bf(b.w);
    ((s16x4*)out)[2 * i] = p0;
    ((s16x4*)out)[2 * i + 1] = p1;
  }
}

// ---- W[K][N] f32 -> Wt[N][K] bf16 ----
__global__ __launch_bounds__(256) void tcvt(const float* __restrict__ W,
                                            unsigned short* __restrict__ Wt, int K, int N) {
  __shared__ float t[32][33];
  const int n0 = blockIdx.x * 32, k0 = blockIdx.y * 32;
  const int c = threadIdx.x & 31, r8 = threadIdx.x >> 5;
#pragma unroll
  for (int p = 0; p < 4; ++p) {
    int r = r8 + p * 8;
    t[r][c] = W[(size_t)(k0 + r) * N + n0 + c];
  }
  __syncthreads();
#pragma unroll
  for (int p = 0; p < 4; ++p) {
    int r = r8 + p * 8;
    Wt[(size_t)(n0 + r) * K + k0 + c] = f2bf(t[c][r]);
  }
}

// ---- bf16 GEMM: C = A[M,1024] @ Bt[N,1024]^T ----
__global__ __launch_bounds__(256) void proj_gemm(
    const unsigned short* __restrict__ A, const unsigned short* __restrict__ Bt,
    unsigned short* __restrict__ C, int N, int mode, float scale)
{
  __shared__ __align__(16) unsigned short As[2][4096];
  __shared__ __align__(16) unsigned short Bs[2][4096];
  const int tid = threadIdx.x, lane = tid & 63, w = tid >> 6;
  const int wr = w >> 1, wc = w & 1;
  const int lrow = lane & 15, lg = lane >> 4;
  const size_t bm = (size_t)blockIdx.x * 128;
  const size_t bn = (size_t)blockIdx.y * 128;
  const int rl = lane >> 2, cq = lane & 3;

  auto stage = [&](int kt, int buf) {
#pragma unroll
    for (int u = 0; u < 2; ++u) {
      int row = w * 32 + u * 16 + rl;
      gload16(A  + (bm + row) * 1024 + kt * 32 + cq * 8, &As[buf][(w * 32 + u * 16) * 32]);
      gload16(Bt + (bn + row) * 1024 + kt * 32 + cq * 8, &Bs[buf][(w * 32 + u * 16) * 32]);
    }
  };

  f32x4 acc[4][4] = {};
  stage(0, 0);
  __syncthreads();

  for (int kt = 0; kt < 32; ++kt) {
    const int cur = kt & 1;
    if (kt + 1 < 32) stage(kt + 1, cur ^ 1);
    bf16x8 af[4], bfr[4];
#pragma unroll
    for (int i = 0; i < 4; ++i)
      af[i] = *(const bf16x8*)&As[cur][(wr * 64 + i * 16 + lrow) * 32 + lg * 8];
#pragma unroll
    for (int j = 0; j < 4; ++j)
      bfr[j] = *(const bf16x8*)&Bs[cur][(wc * 64 + j * 16 + lrow) * 32 + lg * 8];
    __builtin_amdgcn_s_setprio(1);
#pragma unroll
    for (int i = 0; i < 4; ++i)
#pragma unroll
      for (int j = 0; j < 4; ++j)
        acc[i][j] = MFMA16(af[i], bfr[j], acc[i][j]);
    __builtin_amdgcn_s_setprio(0);
    __syncthreads();
  }

  const int orow0 = blockIdx.x * 128 + wr * 64;
  const int ocol0 = blockIdx.y * 128 + wc * 64;
  if (mode == 0) {
#pragma unroll
    for (int i = 0; i < 4; ++i)
#pragma unroll
      for (int j = 0; j < 4; ++j) {
        int col = ocol0 + j * 16 + lrow;
#pragma unroll
        for (int r = 0; r < 4; ++r) {
          int row = orow0 + i * 16 + lg * 4 + r;
          C[(size_t)row * N + col] = f2bf(acc[i][j][r] * scale);
        }
      }
  } else {
#pragma unroll
    for (int i = 0; i < 4; ++i) {
      int m0 = orow0 + i * 16 + lg * 4;
      int bb = m0 >> 11, t = m0 & 2047;
      int tg = t >> 5, tin = t & 31;
#pragma unroll
      for (int j = 0; j < 4; ++j) {
        int e = ocol0 + j * 16 + lrow;
        int eg = e >> 4;
        s16x4 pk;
#pragma unroll
        for (int r = 0; r < 4; ++r) pk[r] = (short)f2bf(acc[i][j][r]);
        *(s16x4*)(C + (size_t)bb * 2097152 + ((size_t)eg * 64 + tg) * 512 + lrow * 32 + tin) = pk;
      }
    }
  }
}

// ---- Flash attention, pipelined: in-register softmax, 2 barriers/iter ----
__global__ __launch_bounds__(512) void attn_kernel(
    const unsigned short* __restrict__ Q,   // [16][2048][256] bf16 (pre-scaled)
    const unsigned short* __restrict__ Kk,  // [16][2048][256] bf16
    const unsigned short* __restrict__ Vp,  // packed [16][64][64][16][32] bf16
    const float* __restrict__ X, float* __restrict__ Out)
{
  __shared__ __align__(16) unsigned short Ks[2][64 * 256];  // K, XOR-swizzled content
  __shared__ __align__(16) unsigned short Ps[2][64 * 72];   // P bf16, dbuf
  __shared__ __align__(8) float PMax[64][2];                // per-colgroup max partials
  __shared__ float al_s[64];
  __shared__ __align__(8) float Lp[64][2];

  const int bid = blockIdx.x;
  const int xcd = bid & 7, slot = bid >> 3;
  const int b = xcd * 2 + (slot >> 5);
  const int q0 = (slot & 31) * 64;

  const int tid = threadIdx.x, lane = tid & 63, w = tid >> 6;
  const int lrow = lane & 15, lg = lane >> 4;
  const int si = w & 3, cg = w >> 2;        // wave covers S rows si*16.., cols cg*32..
  const int myrow0 = si * 16 + lg * 4;

  bf16x8 qf[8];
  const unsigned short* qb = Q + ((size_t)b * 2048 + q0 + si * 16 + lrow) * 256;
#pragma unroll
  for (int ks = 0; ks < 8; ++ks) qf[ks] = *(const bf16x8*)(qb + ks * 32 + lg * 8);

  const unsigned short* kb = Kk + (size_t)b * 2048 * 256;
  const unsigned short* vb = Vp + (size_t)b * 2097152;

  const int srl = lane >> 5, scc = (lane & 31) * 16;
  auto stageK = [&](int tile, int buf) {
#pragma unroll
    for (int is = 0; is < 4; ++is) {
      int row = w * 8 + is * 2 + srl;
      int cb = scc ^ ((row & 7) << 4);
      gload16((const char*)kb + (size_t)(tile * 64 + row) * 512 + cb,
              (char*)&Ks[buf][0] + (w * 8 + is * 2) * 512);
    }
  };

  const int r0 = cg * 32 + lrow;
  const int rx = (r0 & 7) << 4;

  f32x4 s0v, s1v;
  auto computeS = [&](int buf) {
    f32x4 a = {}, c = {};
    const char* kbase = (const char*)&Ks[buf][0];
    __builtin_amdgcn_s_setprio(1);
#pragma unroll
    for (int ks = 0; ks < 8; ++ks) {
      bf16x8 k0 = *(const bf16x8*)(kbase + r0 * 512 + ((ks * 64 + lg * 16) ^ rx));
      bf16x8 k1 = *(const bf16x8*)(kbase + (r0 + 16) * 512 + ((ks * 64 + lg * 16) ^ rx));
      a = MFMA16(qf[ks], k0, a);
      c = MFMA16(qf[ks], k1, c);
    }
    __builtin_amdgcn_s_setprio(0);
    s0v = a; s1v = c;
  };

  float m_reg[4], l_reg[4];
#pragma unroll
  for (int r = 0; r < 4; ++r) { m_reg[r] = -3.0e38f; l_reg[r] = 0.f; }

  auto reduceMax = [&]() {
    float pm[4];
#pragma unroll
    for (int r = 0; r < 4; ++r) pm[r] = fmaxf(s0v[r], s1v[r]);
#pragma unroll
    for (int r = 0; r < 4; ++r) {
      pm[r] = fmaxf(pm[r], __shfl_xor(pm[r], 1));
      pm[r] = fmaxf(pm[r], __shfl_xor(pm[r], 2));
      pm[r] = fmaxf(pm[r], __shfl_xor(pm[r], 4));
      pm[r] = fmaxf(pm[r], __shfl_xor(pm[r], 8));
    }
    if (lrow == 0) {
#pragma unroll
      for (int r = 0; r < 4; ++r) PMax[myrow0 + r][cg] = pm[r];
    }
  };

  // finish softmax for the tile whose S is in s0v/s1v; write P to Ps[buf]
  auto softmaxFin = [&](int buf) {
    float p0[4], p1[4], rs[4], al[4];
#pragma unroll
    for (int r = 0; r < 4; ++r) {
      float2 pp = *(const float2*)&PMax[myrow0 + r][0];
      float mn = fmaxf(m_reg[r], fmaxf(pp.x, pp.y));
      al[r] = __expf(m_reg[r] - mn);
      m_reg[r] = mn;
      p0[r] = __expf(s0v[r] - mn);
      p1[r] = __expf(s1v[r] - mn);
      rs[r] = p0[r] + p1[r];
    }
#pragma unroll
    for (int r = 0; r < 4; ++r) {
      rs[r] += __shfl_xor(rs[r], 1);
      rs[r] += __shfl_xor(rs[r], 2);
      rs[r] += __shfl_xor(rs[r], 4);
      rs[r] += __shfl_xor(rs[r], 8);
      l_reg[r] = l_reg[r] * al[r] + rs[r];
    }
    if (cg == 0 && lrow == 0) {
#pragma unroll
      for (int r = 0; r < 4; ++r) al_s[myrow0 + r] = al[r];
    }
#pragma unroll
    for (int r = 0; r < 4; ++r) {
      Ps[buf][(myrow0 + r) * 72 + cg * 32 + lrow]      = f2bf(p0[r]);
      Ps[buf][(myrow0 + r) * 72 + cg * 32 + 16 + lrow] = f2bf(p1[r]);
    }
  };

  f32x4 acc[4][8] = {};  // rows 16i+(lg*4+r), cols 128w+16n+lrow

  // ---- prologue ----
  stageK(0, 0);
  __syncthreads();
  computeS(0);
  reduceMax();
  stageK(1, 1);
  __syncthreads();           // PMax(0) visible; K1 drained
  softmaxFin(0);
  __syncthreads();           // Ps(0), al_s(0) visible

  // ---- main loop ----
  for (int t = 0; t < 32; ++t) {
    const int cur = t & 1;
    // pre-zone: QK^T(t+1) + max partials + rescale by al(t)
    if (t + 1 < 32) { computeS(cur ^ 1); reduceMax(); }
#pragma unroll
    for (int i = 0; i < 4; ++i) {
      f32x4 a4;
#pragma unroll
      for (int r = 0; r < 4; ++r) a4[r] = al_s[i * 16 + lg * 4 + r];
#pragma unroll
      for (int n = 0; n < 8; ++n) acc[i][n] *= a4;
    }
    __syncthreads();         // barrier A: PMax(t+1) visible
    // zone: K-stage + V prefetch + softmax(t+1) + PV(t)
    if (t + 2 < 32) stageK(t + 2, cur);
    bf16x8 vf[8];
#pragma unroll
    for (int n = 0; n < 8; ++n)
      vf[n] = *(const bf16x8*)(vb + ((size_t)(w * 8 + n) * 64 + (t * 2 + 0)) * 512
                                  + lrow * 32 + lg * 8);
    bf16x8 pf[4];
#pragma unroll
    for (int i = 0; i < 4; ++i)
      pf[i] = *(const bf16x8*)&Ps[cur][(i * 16 + lrow) * 72 + 0 * 32 + lg * 8];
    if (t + 1 < 32) softmaxFin(cur ^ 1);   // VALU hides V/K load latency
    __builtin_amdgcn_s_setprio(1);
#pragma unroll
    for (int n = 0; n < 8; ++n)
#pragma unroll
      for (int i = 0; i < 4; ++i)
        acc[i][n] = MFMA16(pf[i], vf[n], acc[i][n]);
    __builtin_amdgcn_s_setprio(0);
#pragma unroll
    for (int n = 0; n < 8; ++n)
      vf[n] = *(const bf16x8*)(vb + ((size_t)(w * 8 + n) * 64 + (t * 2 + 1)) * 512
                                  + lrow * 32 + lg * 8);
#pragma unroll
    for (int i = 0; i < 4; ++i)
      pf[i] = *(const bf16x8*)&Ps[cur][(i * 16 + lrow) * 72 + 1 * 32 + lg * 8];
    __builtin_amdgcn_s_setprio(1);
#pragma unroll
    for (int n = 0; n < 8; ++n)
#pragma unroll
      for (int i = 0; i < 4; ++i)
        acc[i][n] = MFMA16(pf[i], vf[n], acc[i][n]);
    __builtin_amdgcn_s_setprio(0);
    __syncthreads();         // iter-end: Ps(t+1)/al_s(t+1) visible; K(t+2) drained
  }

  // ---- epilogue: combine l partials, out = acc/l + x ----
  if (lrow == 0) {
#pragma unroll
    for (int r = 0; r < 4; ++r) Lp[myrow0 + r][cg] = l_reg[r];
  }
  __syncthreads();
#pragma unroll
  for (int i = 0; i < 4; ++i) {
#pragma unroll
    for (int r = 0; r < 4; ++r) {
      int row = i * 16 + lg * 4 + r;
      float2 lp = *(const float2*)&Lp[row][0];
      float inv = 1.0f / (lp.x + lp.y);
      const float* xr = X + ((size_t)b * 2048 + q0 + row) * 1024;
      float* orp = Out + ((size_t)b * 2048 + q0 + row) * 1024;
#pragma unroll
      for (int n = 0; n < 8; ++n) {
        int col = w * 128 + n * 16 + lrow;
        orp[col] = acc[i][n][r] * inv + xr[col];
      }
    }
  }
}

extern "C" void kernel_launch(void* const* d_in, const int* in_sizes, int n_in,
                              void* d_out, int out_size, void* d_ws, size_t ws_size,
                              hipStream_t stream) {
  (void)in_sizes; (void)n_in; (void)out_size; (void)ws_size;
  const float* x  = (const float*)d_in[0];
  const float* y  = (const float*)d_in[1];
  const float* Wq = (const float*)d_in[2];
  const float* Wk = (const float*)d_in[3];
  const float* Wv = (const float*)d_in[4];
  float* out = (float*)d_out;

  unsigned short* xb = (unsigned short*)d_out;
  unsigned short* yb = xb + (size_t)16 * 2048 * 1024;

  unsigned short* Wqt = (unsigned short*)d_ws;
  unsigned short* Wkt = Wqt + (size_t)256 * 1024;
  unsigned short* Wvt = Wkt + (size_t)256 * 1024;
  unsigned short* qws = Wvt + (size_t)1024 * 1024;
  unsigned short* kws = qws + (size_t)16 * 2048 * 256;
  unsigned short* vpw = kws + (size_t)16 * 2048 * 256;

  const int n8 = (16 * 2048 * 1024) / 8;
  cvt_bf16<<<2048, 256, 0, stream>>>(x, xb, n8);
  cvt_bf16<<<2048, 256, 0, stream>>>(y, yb, n8);
  tcvt<<<dim3(8, 32),  256, 0, stream>>>(Wq, Wqt, 1024, 256);
  tcvt<<<dim3(8, 32),  256, 0, stream>>>(Wk, Wkt, 1024, 256);
  tcvt<<<dim3(32, 32), 256, 0, stream>>>(Wv, Wvt, 1024, 1024);

  proj_gemm<<<dim3(256, 2), 256, 0, stream>>>(xb, Wqt, qws, 256, 0, 0.03125f);
  proj_gemm<<<dim3(256, 2), 256, 0, stream>>>(yb, Wkt, kws, 256, 0, 1.0f);
  proj_gemm<<<dim3(256, 8), 256, 0, stream>>>(yb, Wvt, vpw, 1024, 2, 1.0f);

  attn_kernel<<<512, 512, 0, stream>>>(qws, kws, vpw, x, out);
}

// Round 4
// 775.152 us; speedup vs baseline: 1.0654x; 1.0654x over previous
//
#include <hip/hip_runtime.h>

typedef __attribute__((ext_vector_type(8))) short bf16x8;
typedef __attribute__((ext_vector_type(4))) short s16x4;
typedef __attribute__((ext_vector_type(4))) float f32x4;

#define MFMA16(a,b,c) __builtin_amdgcn_mfma_f32_16x16x32_bf16((a),(b),(c),0,0,0)

__device__ __forceinline__ unsigned short f2bf(float f) {
  unsigned int u = __float_as_uint(f);
  return (unsigned short)((u + 0x7fffu + ((u >> 16) & 1u)) >> 16);  // RNE
}

__device__ __forceinline__ void gload16(const void* g, void* l) {
  __builtin_amdgcn_global_load_lds((const __attribute__((address_space(1))) void*)g,
                                   (__attribute__((address_space(3))) void*)l, 16, 0, 0);
}

// ---- f32 -> bf16 bulk convert ----
__global__ __launch_bounds__(256) void cvt_bf16(const float* __restrict__ in,
                                                unsigned short* __restrict__ out, int n8) {
  for (int i = blockIdx.x * 256 + threadIdx.x; i < n8; i += gridDim.x * 256) {
    float4 a = ((const float4*)in)[2 * i];
    float4 b = ((const float4*)in)[2 * i + 1];
    s16x4 p0, p1;
    p0[0] = f2bf(a.x); p0[1] = f2bf(a.y); p0[2] = f2bf(a.z); p0[3] = f2bf(a.w);
    p1[0] = f2bf(b.x); p1[1] = f2bf(b.y); p1[2] = f2bf(b.z); p1[3] = f2bf(b.w);
    ((s16x4*)out)[2 * i] = p0;
    ((s16x4*)out)[2 * i + 1] = p1;
  }
}

// ---- W[K][N] f32 -> Wt[N][K] bf16 ----
__global__ __launch_bounds__(256) void tcvt(const float* __restrict__ W,
                                            unsigned short* __restrict__ Wt, int K, int N) {
  __shared__ float t[32][33];
  const int n0 = blockIdx.x * 32, k0 = blockIdx.y * 32;
  const int c = threadIdx.x & 31, r8 = threadIdx.x >> 5;
#pragma unroll
  for (int p = 0; p < 4; ++p) {
    int r = r8 + p * 8;
    t[r][c] = W[(size_t)(k0 + r) * N + n0 + c];
  }
  __syncthreads();
#pragma unroll
  for (int p = 0; p < 4; ++p) {
    int r = r8 + p * 8;
    Wt[(size_t)(n0 + r) * K + k0 + c] = f2bf(t[c][r]);
  }
}

// ---- bf16 GEMM: C = A[M,1024] @ Bt[N,1024]^T ----
__global__ __launch_bounds__(256) void proj_gemm(
    const unsigned short* __restrict__ A, const unsigned short* __restrict__ Bt,
    unsigned short* __restrict__ C, int N, int mode, float scale)
{
  __shared__ __align__(16) unsigned short As[2][4096];
  __shared__ __align__(16) unsigned short Bs[2][4096];
  const int tid = threadIdx.x, lane = tid & 63, w = tid >> 6;
  const int wr = w >> 1, wc = w & 1;
  const int lrow = lane & 15, lg = lane >> 4;
  const size_t bm = (size_t)blockIdx.x * 128;
  const size_t bn = (size_t)blockIdx.y * 128;
  const int rl = lane >> 2, cq = lane & 3;

  auto stage = [&](int kt, int buf) {
#pragma unroll
    for (int u = 0; u < 2; ++u) {
      int row = w * 32 + u * 16 + rl;
      gload16(A  + (bm + row) * 1024 + kt * 32 + cq * 8, &As[buf][(w * 32 + u * 16) * 32]);
      gload16(Bt + (bn + row) * 1024 + kt * 32 + cq * 8, &Bs[buf][(w * 32 + u * 16) * 32]);
    }
  };

  f32x4 acc[4][4] = {};
  stage(0, 0);
  __syncthreads();

  for (int kt = 0; kt < 32; ++kt) {
    const int cur = kt & 1;
    if (kt + 1 < 32) stage(kt + 1, cur ^ 1);
    bf16x8 af[4], bfr[4];
#pragma unroll
    for (int i = 0; i < 4; ++i)
      af[i] = *(const bf16x8*)&As[cur][(wr * 64 + i * 16 + lrow) * 32 + lg * 8];
#pragma unroll
    for (int j = 0; j < 4; ++j)
      bfr[j] = *(const bf16x8*)&Bs[cur][(wc * 64 + j * 16 + lrow) * 32 + lg * 8];
    __builtin_amdgcn_s_setprio(1);
#pragma unroll
    for (int i = 0; i < 4; ++i)
#pragma unroll
      for (int j = 0; j < 4; ++j)
        acc[i][j] = MFMA16(af[i], bfr[j], acc[i][j]);
    __builtin_amdgcn_s_setprio(0);
    __syncthreads();
  }

  const int orow0 = blockIdx.x * 128 + wr * 64;
  const int ocol0 = blockIdx.y * 128 + wc * 64;
  if (mode == 0) {
#pragma unroll
    for (int i = 0; i < 4; ++i)
#pragma unroll
      for (int j = 0; j < 4; ++j) {
        int col = ocol0 + j * 16 + lrow;
#pragma unroll
        for (int r = 0; r < 4; ++r) {
          int row = orow0 + i * 16 + lg * 4 + r;
          C[(size_t)row * N + col] = f2bf(acc[i][j][r] * scale);
        }
      }
  } else {
#pragma unroll
    for (int i = 0; i < 4; ++i) {
      int m0 = orow0 + i * 16 + lg * 4;
      int bb = m0 >> 11, t = m0 & 2047;
      int tg = t >> 5, tin = t & 31;
#pragma unroll
      for (int j = 0; j < 4; ++j) {
        int e = ocol0 + j * 16 + lrow;
        int eg = e >> 4;
        s16x4 pk;
#pragma unroll
        for (int r = 0; r < 4; ++r) pk[r] = (short)f2bf(acc[i][j][r]);
        *(s16x4*)(C + (size_t)bb * 2097152 + ((size_t)eg * 64 + tg) * 512 + lrow * 32 + tin) = pk;
      }
    }
  }
}

// ---- Flash attention: round-2 structure + counted-vmcnt barriers (T4) ----
__global__ __launch_bounds__(512) void attn_kernel(
    const unsigned short* __restrict__ Q,   // [16][2048][256] bf16 (pre-scaled)
    const unsigned short* __restrict__ Kk,  // [16][2048][256] bf16
    const unsigned short* __restrict__ Vp,  // packed [16][64][64][16][32] bf16
    const float* __restrict__ X, float* __restrict__ Out)
{
  __shared__ __align__(16) unsigned short Ks[2][64 * 256];  // XOR-swizzled content
  __shared__ __align__(16) float Ss[64 * 68];
  __shared__ __align__(16) unsigned short Ps[64 * 72];
  __shared__ float m_s[64], l_s[64], al_s[64];

  const int bid = blockIdx.x;
  const int xcd = bid & 7, slot = bid >> 3;
  const int b = xcd * 2 + (slot >> 5);
  const int q0 = (slot & 31) * 64;

  const int tid = threadIdx.x, lane = tid & 63, w = tid >> 6;
  const int lrow = lane & 15, lg = lane >> 4;
  const int si = w & 3, sj0 = (w >> 2) * 2;

  if (tid < 64) { m_s[tid] = -3.0e38f; l_s[tid] = 0.f; }

  bf16x8 qf[8];
  const unsigned short* qb = Q + ((size_t)b * 2048 + q0 + si * 16 + lrow) * 256;
#pragma unroll
  for (int ks = 0; ks < 8; ++ks) qf[ks] = *(const bf16x8*)(qb + ks * 32 + lg * 8);

  const unsigned short* kb = Kk + (size_t)b * 2048 * 256;
  const unsigned short* vb = Vp + (size_t)b * 2097152;

  const int srl = lane >> 5, scc = (lane & 31) * 16;
  auto stageK = [&](int tile, int buf) {
#pragma unroll
    for (int is = 0; is < 4; ++is) {
      int row = w * 8 + is * 2 + srl;
      int cb = scc ^ ((row & 7) << 4);
      gload16((const char*)kb + (size_t)(tile * 64 + row) * 512 + cb,
              (char*)&Ks[buf][0] + (w * 8 + is * 2) * 512);
    }
  };

  const int r0 = sj0 * 16 + lrow;
  const int rx = (r0 & 7) << 4;

  f32x4 acc[4][8] = {};  // rows 16i+(lg*4+r), cols 128w+16n+lrow
  bf16x8 vf0[8];

  // ---- prologue: two K tiles in flight; wait only the first ----
  stageK(0, 0);
  stageK(1, 1);
  asm volatile("s_waitcnt vmcnt(4)" ::: "memory");   // K(0) landed; K(1) in flight
  __builtin_amdgcn_sched_barrier(0);

  for (int t = 0; t < 32; ++t) {
    const int cur = t & 1;
    // K(t) landed per-wave (in-order vmcnt: prior iter's V waits cover it)
    __builtin_amdgcn_s_barrier();
    __builtin_amdgcn_sched_barrier(0);

    // ---- P1: QK^T -> Ss ----
    {
      f32x4 s0v = {}, s1v = {};
      const char* kbase = (const char*)&Ks[cur][0];
      __builtin_amdgcn_s_setprio(1);
#pragma unroll
      for (int ks = 0; ks < 8; ++ks) {
        bf16x8 k0 = *(const bf16x8*)(kbase + r0 * 512 + ((ks * 64 + lg * 16) ^ rx));
        bf16x8 k1 = *(const bf16x8*)(kbase + (r0 + 16) * 512 + ((ks * 64 + lg * 16) ^ rx));
        s0v = MFMA16(qf[ks], k0, s0v);
        s1v = MFMA16(qf[ks], k1, s1v);
      }
      __builtin_amdgcn_s_setprio(0);
#pragma unroll
      for (int r = 0; r < 4; ++r) {
        Ss[(si * 16 + lg * 4 + r) * 68 + sj0 * 16 + lrow]      = s0v[r];
        Ss[(si * 16 + lg * 4 + r) * 68 + sj0 * 16 + 16 + lrow] = s1v[r];
      }
    }
    asm volatile("s_waitcnt lgkmcnt(0)" ::: "memory");
    __builtin_amdgcn_s_barrier();
    __builtin_amdgcn_sched_barrier(0);

    // ---- P2: prefetch V kk0; online softmax ----
#pragma unroll
    for (int n = 0; n < 8; ++n)
      vf0[n] = *(const bf16x8*)(vb + ((size_t)(w * 8 + n) * 64 + (t * 2 + 0)) * 512
                                   + lrow * 32 + lg * 8);
    {
      const int row = tid >> 3, sl = tid & 7;
      float4 a0 = *(const float4*)&Ss[row * 68 + sl * 8];
      float4 a1 = *(const float4*)&Ss[row * 68 + sl * 8 + 4];
      float sv[8] = {a0.x, a0.y, a0.z, a0.w, a1.x, a1.y, a1.z, a1.w};
      float mx = sv[0];
#pragma unroll
      for (int j = 1; j < 8; ++j) mx = fmaxf(mx, sv[j]);
      mx = fmaxf(mx, __shfl_xor(mx, 1));
      mx = fmaxf(mx, __shfl_xor(mx, 2));
      mx = fmaxf(mx, __shfl_xor(mx, 4));
      float mo = m_s[row];            // wave-lockstep: read precedes sl==0 write
      float mn = fmaxf(mo, mx);
      float p[8], sum = 0.f;
#pragma unroll
      for (int j = 0; j < 8; ++j) { p[j] = __expf(sv[j] - mn); sum += p[j]; }
      sum += __shfl_xor(sum, 1);
      sum += __shfl_xor(sum, 2);
      sum += __shfl_xor(sum, 4);
      if (sl == 0) {
        float al = __expf(mo - mn);
        al_s[row] = al;
        m_s[row]  = mn;
        l_s[row]  = l_s[row] * al + sum;
      }
      bf16x8 pk;
#pragma unroll
      for (int j = 0; j < 8; ++j) pk[j] = (short)f2bf(p[j]);
      *(bf16x8*)&Ps[row * 72 + sl * 8] = pk;
    }
    asm volatile("s_waitcnt lgkmcnt(0)" ::: "memory");
    __builtin_amdgcn_s_barrier();
    __builtin_amdgcn_sched_barrier(0);

    // ---- P3: rescale, PV kk0 (prefetched V), PV kk1, then stage K(t+2) ----
    {
#pragma unroll
      for (int i = 0; i < 4; ++i) {
        f32x4 a4;
#pragma unroll
        for (int r = 0; r < 4; ++r) a4[r] = al_s[i * 16 + lg * 4 + r];
#pragma unroll
        for (int n = 0; n < 8; ++n) acc[i][n] *= a4;
      }
      bf16x8 pf[4];
#pragma unroll
      for (int i = 0; i < 4; ++i)
        pf[i] = *(const bf16x8*)&Ps[(i * 16 + lrow) * 72 + 0 * 32 + lg * 8];
      bf16x8 vf1[8];
#pragma unroll
      for (int n = 0; n < 8; ++n)   // issue kk1 loads; kk0 MFMA hides latency
        vf1[n] = *(const bf16x8*)(vb + ((size_t)(w * 8 + n) * 64 + (t * 2 + 1)) * 512
                                     + lrow * 32 + lg * 8);
      __builtin_amdgcn_s_setprio(1);
#pragma unroll
      for (int n = 0; n < 8; ++n)
#pragma unroll
        for (int i = 0; i < 4; ++i)
          acc[i][n] = MFMA16(pf[i], vf0[n], acc[i][n]);
      __builtin_amdgcn_s_setprio(0);
#pragma unroll
      for (int i = 0; i < 4; ++i)
        pf[i] = *(const bf16x8*)&Ps[(i * 16 + lrow) * 72 + 1 * 32 + lg * 8];
      __builtin_amdgcn_s_setprio(1);
#pragma unroll
      for (int n = 0; n < 8; ++n)
#pragma unroll
        for (int i = 0; i < 4; ++i)
          acc[i][n] = MFMA16(pf[i], vf1[n], acc[i][n]);
      __builtin_amdgcn_s_setprio(0);
    }
    if (t + 2 < 32) stageK(t + 2, cur);  // issued LAST: V waits never drain it
  }

  // ---- epilogue: out = acc / l + x ----
#pragma unroll
  for (int i = 0; i < 4; ++i) {
#pragma unroll
    for (int r = 0; r < 4; ++r) {
      int row = i * 16 + lg * 4 + r;
      float inv = 1.0f / l_s[row];
      const float* xr = X + ((size_t)b * 2048 + q0 + row) * 1024;
      float* orp = Out + ((size_t)b * 2048 + q0 + row) * 1024;
#pragma unroll
      for (int n = 0; n < 8; ++n) {
        int col = w * 128 + n * 16 + lrow;
        orp[col] = acc[i][n][r] * inv + xr[col];
      }
    }
  }
}

extern "C" void kernel_launch(void* const* d_in, const int* in_sizes, int n_in,
                              void* d_out, int out_size, void* d_ws, size_t ws_size,
                              hipStream_t stream) {
  (void)in_sizes; (void)n_in; (void)out_size; (void)ws_size;
  const float* x  = (const float*)d_in[0];
  const float* y  = (const float*)d_in[1];
  const float* Wq = (const float*)d_in[2];
  const float* Wk = (const float*)d_in[3];
  const float* Wv = (const float*)d_in[4];
  float* out = (float*)d_out;

  unsigned short* xb = (unsigned short*)d_out;
  unsigned short* yb = xb + (size_t)16 * 2048 * 1024;

  unsigned short* Wqt = (unsigned short*)d_ws;
  unsigned short* Wkt = Wqt + (size_t)256 * 1024;
  unsigned short* Wvt = Wkt + (size_t)256 * 1024;
  unsigned short* qws = Wvt + (size_t)1024 * 1024;
  unsigned short* kws = qws + (size_t)16 * 2048 * 256;
  unsigned short* vpw = kws + (size_t)16 * 2048 * 256;

  const int n8 = (16 * 2048 * 1024) / 8;
  cvt_bf16<<<2048, 256, 0, stream>>>(x, xb, n8);
  cvt_bf16<<<2048, 256, 0, stream>>>(y, yb, n8);
  tcvt<<<dim3(8, 32),  256, 0, stream>>>(Wq, Wqt, 1024, 256);
  tcvt<<<dim3(8, 32),  256, 0, stream>>>(Wk, Wkt, 1024, 256);
  tcvt<<<dim3(32, 32), 256, 0, stream>>>(Wv, Wvt, 1024, 1024);

  proj_gemm<<<dim3(256, 2), 256, 0, stream>>>(xb, Wqt, qws, 256, 0, 0.03125f);
  proj_gemm<<<dim3(256, 2), 256, 0, stream>>>(yb, Wkt, kws, 256, 0, 1.0f);
  proj_gemm<<<dim3(256, 8), 256, 0, stream>>>(yb, Wvt, vpw, 1024, 2, 1.0f);

  attn_kernel<<<512, 512, 0, stream>>>(qws, kws, vpw, x, out);
}

// Round 5
// 654.294 us; speedup vs baseline: 1.2622x; 1.1847x over previous
//
#include <hip/hip_runtime.h>

typedef __attribute__((ext_vector_type(8))) short bf16x8;
typedef __attribute__((ext_vector_type(4))) short s16x4;
typedef __attribute__((ext_vector_type(4))) float f32x4;

#define MFMA16(a,b,c) __builtin_amdgcn_mfma_f32_16x16x32_bf16((a),(b),(c),0,0,0)

__device__ __forceinline__ unsigned short f2bf(float f) {
  unsigned int u = __float_as_uint(f);
  return (unsigned short)((u + 0x7fffu + ((u >> 16) & 1u)) >> 16);  // RNE
}

__device__ __forceinline__ void gload16(const void* g, void* l) {
  __builtin_amdgcn_global_load_lds((const __attribute__((address_space(1))) void*)g,
                                   (__attribute__((address_space(3))) void*)l, 16, 0, 0);
}

// ---- f32 -> bf16 bulk convert ----
__global__ __launch_bounds__(256) void cvt_bf16(const float* __restrict__ in,
                                                unsigned short* __restrict__ out, int n8) {
  for (int i = blockIdx.x * 256 + threadIdx.x; i < n8; i += gridDim.x * 256) {
    float4 a = ((const float4*)in)[2 * i];
    float4 b = ((const float4*)in)[2 * i + 1];
    s16x4 p0, p1;
    p0[0] = f2bf(a.x); p0[1] = f2bf(a.y); p0[2] = f2bf(a.z); p0[3] = f2bf(a.w);
    p1[0] = f2bf(b.x); p1[1] = f2bf(b.y); p1[2] = f2bf(b.z); p1[3] = f2bf(b.w);
    ((s16x4*)out)[2 * i] = p0;
    ((s16x4*)out)[2 * i + 1] = p1;
  }
}

// ---- W[K][N] f32 -> Wt[N][K] bf16 ----
__global__ __launch_bounds__(256) void tcvt(const float* __restrict__ W,
                                            unsigned short* __restrict__ Wt, int K, int N) {
  __shared__ float t[32][33];
  const int n0 = blockIdx.x * 32, k0 = blockIdx.y * 32;
  const int c = threadIdx.x & 31, r8 = threadIdx.x >> 5;
#pragma unroll
  for (int p = 0; p < 4; ++p) {
    int r = r8 + p * 8;
    t[r][c] = W[(size_t)(k0 + r) * N + n0 + c];
  }
  __syncthreads();
#pragma unroll
  for (int p = 0; p < 4; ++p) {
    int r = r8 + p * 8;
    Wt[(size_t)(n0 + r) * K + k0 + c] = f2bf(t[c][r]);
  }
}

// ---- bf16 GEMM: C = A[M,1024] @ Bt[N,1024]^T ----
__global__ __launch_bounds__(256) void proj_gemm(
    const unsigned short* __restrict__ A, const unsigned short* __restrict__ Bt,
    unsigned short* __restrict__ C, int N, int mode, float scale)
{
  __shared__ __align__(16) unsigned short As[2][4096];
  __shared__ __align__(16) unsigned short Bs[2][4096];
  const int tid = threadIdx.x, lane = tid & 63, w = tid >> 6;
  const int wr = w >> 1, wc = w & 1;
  const int lrow = lane & 15, lg = lane >> 4;
  const size_t bm = (size_t)blockIdx.x * 128;
  const size_t bn = (size_t)blockIdx.y * 128;
  const int rl = lane >> 2, cq = lane & 3;

  auto stage = [&](int kt, int buf) {
#pragma unroll
    for (int u = 0; u < 2; ++u) {
      int row = w * 32 + u * 16 + rl;
      gload16(A  + (bm + row) * 1024 + kt * 32 + cq * 8, &As[buf][(w * 32 + u * 16) * 32]);
      gload16(Bt + (bn + row) * 1024 + kt * 32 + cq * 8, &Bs[buf][(w * 32 + u * 16) * 32]);
    }
  };

  f32x4 acc[4][4] = {};
  stage(0, 0);
  __syncthreads();

  for (int kt = 0; kt < 32; ++kt) {
    const int cur = kt & 1;
    if (kt + 1 < 32) stage(kt + 1, cur ^ 1);
    bf16x8 af[4], bfr[4];
#pragma unroll
    for (int i = 0; i < 4; ++i)
      af[i] = *(const bf16x8*)&As[cur][(wr * 64 + i * 16 + lrow) * 32 + lg * 8];
#pragma unroll
    for (int j = 0; j < 4; ++j)
      bfr[j] = *(const bf16x8*)&Bs[cur][(wc * 64 + j * 16 + lrow) * 32 + lg * 8];
    __builtin_amdgcn_s_setprio(1);
#pragma unroll
    for (int i = 0; i < 4; ++i)
#pragma unroll
      for (int j = 0; j < 4; ++j)
        acc[i][j] = MFMA16(af[i], bfr[j], acc[i][j]);
    __builtin_amdgcn_s_setprio(0);
    __syncthreads();
  }

  const int orow0 = blockIdx.x * 128 + wr * 64;
  const int ocol0 = blockIdx.y * 128 + wc * 64;
  if (mode == 0) {
#pragma unroll
    for (int i = 0; i < 4; ++i)
#pragma unroll
      for (int j = 0; j < 4; ++j) {
        int col = ocol0 + j * 16 + lrow;
#pragma unroll
        for (int r = 0; r < 4; ++r) {
          int row = orow0 + i * 16 + lg * 4 + r;
          C[(size_t)row * N + col] = f2bf(acc[i][j][r] * scale);
        }
      }
  } else {
#pragma unroll
    for (int i = 0; i < 4; ++i) {
      int m0 = orow0 + i * 16 + lg * 4;
      int bb = m0 >> 11, t = m0 & 2047;
      int tg = t >> 5, tin = t & 31;
#pragma unroll
      for (int j = 0; j < 4; ++j) {
        int e = ocol0 + j * 16 + lrow;
        int eg = e >> 4;
        s16x4 pk;
#pragma unroll
        for (int r = 0; r < 4; ++r) pk[r] = (short)f2bf(acc[i][j][r]);
        *(s16x4*)(C + (size_t)bb * 2097152 + ((size_t)eg * 64 + tg) * 512 + lrow * 32 + tin) = pk;
      }
    }
  }
}

// ---- Flash attention: tri-buffered K, in-reg softmax, 2 lgkm-only barriers/iter ----
__global__ __launch_bounds__(512) void attn_kernel(
    const unsigned short* __restrict__ Q,   // [16][2048][256] bf16 (pre-scaled)
    const unsigned short* __restrict__ Kk,  // [16][2048][256] bf16
    const unsigned short* __restrict__ Vp,  // packed [16][64][64][16][32] bf16
    const float* __restrict__ X, float* __restrict__ Out)
{
  __shared__ __align__(16) unsigned short Ks[3][64 * 256];  // 96KB, XOR-swizzled content
  __shared__ __align__(16) unsigned short Ps[64 * 72];      // 9KB
  __shared__ __align__(8) float PMax[64][2];
  __shared__ float al_s[64];
  __shared__ __align__(8) float Lp[64][2];

  const int bid = blockIdx.x;
  const int xcd = bid & 7, slot = bid >> 3;
  const int b = xcd * 2 + (slot >> 5);
  const int q0 = (slot & 31) * 64;

  const int tid = threadIdx.x, lane = tid & 63, w = tid >> 6;
  const int lrow = lane & 15, lg = lane >> 4;
  const int si = w & 3, cg = w >> 2;        // wave: S rows si*16..+16, cols cg*32..+32
  const int myrow0 = si * 16 + lg * 4;

  bf16x8 qf[8];
  const unsigned short* qb = Q + ((size_t)b * 2048 + q0 + si * 16 + lrow) * 256;
#pragma unroll
  for (int ks = 0; ks < 8; ++ks) qf[ks] = *(const bf16x8*)(qb + ks * 32 + lg * 8);

  const unsigned short* kb = Kk + (size_t)b * 2048 * 256;
  const unsigned short* vb = Vp + (size_t)b * 2097152;

  const int srl = lane >> 5, scc = (lane & 31) * 16;
  auto stageK = [&](int tile, int buf) {
#pragma unroll
    for (int is = 0; is < 4; ++is) {
      int row = w * 8 + is * 2 + srl;
      int cb = scc ^ ((row & 7) << 4);
      gload16((const char*)kb + (size_t)(tile * 64 + row) * 512 + cb,
              (char*)&Ks[buf][0] + (w * 8 + is * 2) * 512);
    }
  };

  const int r0 = cg * 32 + lrow;
  const int rx = (r0 & 7) << 4;

  float m_reg[4], l_reg[4];
#pragma unroll
  for (int r = 0; r < 4; ++r) { m_reg[r] = -3.0e38f; l_reg[r] = 0.f; }

  f32x4 acc[4][8] = {};  // out rows 16i+(lg*4+r), cols 128w+16n+lrow

  // ---- prologue: K0,K1 in flight; own K0 parts done -> barrier => K0 staged ----
  stageK(0, 0);
  stageK(1, 1);
  asm volatile("s_waitcnt vmcnt(4)" ::: "memory");
  __builtin_amdgcn_s_barrier();

  for (int t = 0; t < 32; ++t) {
    const int cur = t % 3;
    // ---- P1: QK^T in registers (4 indep MFMA chains) + max partials ----
    f32x4 s0v, s1v;
    {
      f32x4 a0 = {}, a1 = {}, c0 = {}, c1 = {};
      const char* kbase = (const char*)&Ks[cur][0];
      __builtin_amdgcn_s_setprio(1);
#pragma unroll
      for (int ks = 0; ks < 8; ks += 2) {
        bf16x8 k0a = *(const bf16x8*)(kbase + r0 * 512 + ((ks * 64 + lg * 16) ^ rx));
        bf16x8 k1a = *(const bf16x8*)(kbase + (r0 + 16) * 512 + ((ks * 64 + lg * 16) ^ rx));
        bf16x8 k0b = *(const bf16x8*)(kbase + r0 * 512 + (((ks + 1) * 64 + lg * 16) ^ rx));
        bf16x8 k1b = *(const bf16x8*)(kbase + (r0 + 16) * 512 + (((ks + 1) * 64 + lg * 16) ^ rx));
        a0 = MFMA16(qf[ks], k0a, a0);
        c0 = MFMA16(qf[ks], k1a, c0);
        a1 = MFMA16(qf[ks + 1], k0b, a1);
        c1 = MFMA16(qf[ks + 1], k1b, c1);
      }
      __builtin_amdgcn_s_setprio(0);
      s0v = a0 + a1; s1v = c0 + c1;
    }
    {
      float pm[4];
#pragma unroll
      for (int r = 0; r < 4; ++r) pm[r] = fmaxf(s0v[r], s1v[r]);
#pragma unroll
      for (int r = 0; r < 4; ++r) {
        pm[r] = fmaxf(pm[r], __shfl_xor(pm[r], 1));
        pm[r] = fmaxf(pm[r], __shfl_xor(pm[r], 2));
        pm[r] = fmaxf(pm[r], __shfl_xor(pm[r], 4));
        pm[r] = fmaxf(pm[r], __shfl_xor(pm[r], 8));
      }
      if (lrow == 0) {
#pragma unroll
        for (int r = 0; r < 4; ++r) PMax[myrow0 + r][cg] = pm[r];
      }
    }
    asm volatile("s_waitcnt lgkmcnt(0)" ::: "memory");
    __builtin_amdgcn_s_barrier();            // bar1: PMax visible (no vmem drain)

    // ---- P1b: finish softmax in-reg; write Ps/al_s; issue K(t+2) stage ----
    {
      float p0[4], p1[4], rs[4], al[4];
#pragma unroll
      for (int r = 0; r < 4; ++r) {
        float2 pp = *(const float2*)&PMax[myrow0 + r][0];
        float mn = fmaxf(m_reg[r], fmaxf(pp.x, pp.y));
        al[r] = __expf(m_reg[r] - mn);
        m_reg[r] = mn;
        p0[r] = __expf(s0v[r] - mn);
        p1[r] = __expf(s1v[r] - mn);
        rs[r] = p0[r] + p1[r];
      }
#pragma unroll
      for (int r = 0; r < 4; ++r) {
        rs[r] += __shfl_xor(rs[r], 1);
        rs[r] += __shfl_xor(rs[r], 2);
        rs[r] += __shfl_xor(rs[r], 4);
        rs[r] += __shfl_xor(rs[r], 8);
        l_reg[r] = l_reg[r] * al[r] + rs[r];
      }
      if (cg == 0 && lrow == 0) {
#pragma unroll
        for (int r = 0; r < 4; ++r) al_s[myrow0 + r] = al[r];
      }
#pragma unroll
      for (int r = 0; r < 4; ++r) {
        Ps[(myrow0 + r) * 72 + cg * 32 + lrow]      = f2bf(p0[r]);
        Ps[(myrow0 + r) * 72 + cg * 32 + 16 + lrow] = f2bf(p1[r]);
      }
    }
    if (t + 2 < 32) stageK(t + 2, (t + 2) % 3);   // vmem: drained by P3's V waits
    asm volatile("s_waitcnt lgkmcnt(0)" ::: "memory");
    __builtin_amdgcn_s_barrier();            // bar2: Ps/al_s visible (no vmem drain)

    // ---- P3: rescale + PV (V direct from L2-resident packed tiles) ----
    {
      bf16x8 pf[4];
#pragma unroll
      for (int i = 0; i < 4; ++i)
        pf[i] = *(const bf16x8*)&Ps[(i * 16 + lrow) * 72 + 0 * 32 + lg * 8];
      bf16x8 vf[8];
#pragma unroll
      for (int n = 0; n < 8; ++n)
        vf[n] = *(const bf16x8*)(vb + ((size_t)(w * 8 + n) * 64 + (t * 2 + 0)) * 512
                                    + lrow * 32 + lg * 8);
#pragma unroll
      for (int i = 0; i < 4; ++i) {
        f32x4 a4;
#pragma unroll
        for (int r = 0; r < 4; ++r) a4[r] = al_s[i * 16 + lg * 4 + r];
#pragma unroll
        for (int n = 0; n < 8; ++n) acc[i][n] *= a4;
      }
      __builtin_amdgcn_s_setprio(1);
#pragma unroll
      for (int n = 0; n < 8; ++n)
#pragma unroll
        for (int i = 0; i < 4; ++i)
          acc[i][n] = MFMA16(pf[i], vf[n], acc[i][n]);
      __builtin_amdgcn_s_setprio(0);
#pragma unroll
      for (int i = 0; i < 4; ++i)
        pf[i] = *(const bf16x8*)&Ps[(i * 16 + lrow) * 72 + 1 * 32 + lg * 8];
#pragma unroll
      for (int n = 0; n < 8; ++n)
        vf[n] = *(const bf16x8*)(vb + ((size_t)(w * 8 + n) * 64 + (t * 2 + 1)) * 512
                                    + lrow * 32 + lg * 8);
      __builtin_amdgcn_s_setprio(1);
#pragma unroll
      for (int n = 0; n < 8; ++n)
#pragma unroll
        for (int i = 0; i < 4; ++i)
          acc[i][n] = MFMA16(pf[i], vf[n], acc[i][n]);
      __builtin_amdgcn_s_setprio(0);
    }
    // no iter-end barrier: next P1 reads Ks[(t+1)%3], staged 2 iters ago
  }

  // ---- epilogue: combine l partials, out = acc/l + x ----
  if (lrow == 0) {
#pragma unroll
    for (int r = 0; r < 4; ++r) Lp[myrow0 + r][cg] = l_reg[r];
  }
  __syncthreads();
#pragma unroll
  for (int i = 0; i < 4; ++i) {
#pragma unroll
    for (int r = 0; r < 4; ++r) {
      int row = i * 16 + lg * 4 + r;
      float2 lp = *(const float2*)&Lp[row][0];
      float inv = 1.0f / (lp.x + lp.y);
      const float* xr = X + ((size_t)b * 2048 + q0 + row) * 1024;
      float* orp = Out + ((size_t)b * 2048 + q0 + row) * 1024;
#pragma unroll
      for (int n = 0; n < 8; ++n) {
        int col = w * 128 + n * 16 + lrow;
        orp[col] = acc[i][n][r] * inv + xr[col];
      }
    }
  }
}

extern "C" void kernel_launch(void* const* d_in, const int* in_sizes, int n_in,
                              void* d_out, int out_size, void* d_ws, size_t ws_size,
                              hipStream_t stream) {
  (void)in_sizes; (void)n_in; (void)out_size; (void)ws_size;
  const float* x  = (const float*)d_in[0];
  const float* y  = (const float*)d_in[1];
  const float* Wq = (const float*)d_in[2];
  const float* Wk = (const float*)d_in[3];
  const float* Wv = (const float*)d_in[4];
  float* out = (float*)d_out;

  unsigned short* xb = (unsigned short*)d_out;
  unsigned short* yb = xb + (size_t)16 * 2048 * 1024;

  unsigned short* Wqt = (unsigned short*)d_ws;
  unsigned short* Wkt = Wqt + (size_t)256 * 1024;
  unsigned short* Wvt = Wkt + (size_t)256 * 1024;
  unsigned short* qws = Wvt + (size_t)1024 * 1024;
  unsigned short* kws = qws + (size_t)16 * 2048 * 256;
  unsigned short* vpw = kws + (size_t)16 * 2048 * 256;

  const int n8 = (16 * 2048 * 1024) / 8;
  cvt_bf16<<<2048, 256, 0, stream>>>(x, xb, n8);
  cvt_bf16<<<2048, 256, 0, stream>>>(y, yb, n8);
  tcvt<<<dim3(8, 32),  256, 0, stream>>>(Wq, Wqt, 1024, 256);
  tcvt<<<dim3(8, 32),  256, 0, stream>>>(Wk, Wkt, 1024, 256);
  tcvt<<<dim3(32, 32), 256, 0, stream>>>(Wv, Wvt, 1024, 1024);

  proj_gemm<<<dim3(256, 2), 256, 0, stream>>>(xb, Wqt, qws, 256, 0, 0.03125f);
  proj_gemm<<<dim3(256, 2), 256, 0, stream>>>(yb, Wkt, kws, 256, 0, 1.0f);
  proj_gemm<<<dim3(256, 8), 256, 0, stream>>>(yb, Wvt, vpw, 1024, 2, 1.0f);

  attn_kernel<<<512, 512, 0, stream>>>(qws, kws, vpw, x, out);
}